// Round 14
// baseline (2373.943 us; speedup 1.0000x reference)
//
#include <hip/hip_runtime.h>

#define NPTS 4096
#define NB   4
#define CH   512
#define TOT  (NB * NPTS)   // 16384
#define KNN  5

// ---------------- transpose (naive gather): x [B,C,N] -> xt [B*N, C] ----------------
__global__ __launch_bounds__(256) void transpose_naive(const float* __restrict__ x,
                                                       float* __restrict__ xt) {
    const int p = blockIdx.x;            // 0..16383
    const int b = p >> 12, n = p & (NPTS - 1);
#pragma unroll
    for (int it = 0; it < 2; ++it) {
        int c = threadIdx.x + it * 256;
        xt[(size_t)p * CH + c] = x[((size_t)b * CH + c) * NPTS + n];
    }
}

// ---------------- KNN: SOP d2, BLAS-style FMA dot, unfused combine ----------------
// d2   = fl(fl(x*x) + fl(y*y))                       (reduce_sum of mul: scalar SOP)
// dot  = fma(y_n, y_m, fl(x_n*x_m))                  (np.matmul/BLAS sgemm K=2, K ascending)
// dist = fl( fl(d2n + d2m) - fl(2*dot) )             (elementwise ops, unfused)
// ties -> lowest index (exact ties shown impossible at f32: dist ulp ~5.8e-11 vs gap 7.8e-5).
// contract(off) pins everything except the explicit fmaf.
__global__ __launch_bounds__(256) void knn_kernel(const float* __restrict__ pos,
                                                  int* __restrict__ idxOut) {
#pragma clang fp contract(off)
    __shared__ float cx[NPTS];
    __shared__ float cy[NPTS];
    __shared__ float d2s[NPTS];
    const int b = blockIdx.x >> 4;                         // 16 blocks per batch
    const int n = ((blockIdx.x & 15) << 8) + threadIdx.x;  // 0..4095
    const float2* P = (const float2*)(pos + (size_t)b * NPTS * 2);
    for (int m = threadIdx.x; m < NPTS; m += 256) {
        float2 c = P[m];
        cx[m] = c.x; cy[m] = c.y;
        float xx = c.x * c.x;
        float yy = c.y * c.y;
        d2s[m] = xx + yy;
    }
    __syncthreads();
    const float xq = cx[n], yq = cy[n], d2q = d2s[n];
    float bd0 = 3.4e38f, bd1 = 3.4e38f, bd2 = 3.4e38f, bd3 = 3.4e38f, bd4 = 3.4e38f;
    int   bi0 = 0, bi1 = 0, bi2 = 0, bi3 = 0, bi4 = 0;
    for (int m = 0; m < NPTS; ++m) {
        float px  = xq * cx[m];                         // rounded mul (k=0 term)
        float dot = __builtin_fmaf(yq, cy[m], px);      // single-rounded fma (k=1 term)
        float s   = d2q + d2s[m];
        float t2  = 2.0f * dot;
        float dist = s - t2;
        if (dist < bd4) {
            bd4 = dist; bi4 = m;
            if (bd4 < bd3) { float t = bd3; bd3 = bd4; bd4 = t; int u = bi3; bi3 = bi4; bi4 = u; }
            if (bd3 < bd2) { float t = bd2; bd2 = bd3; bd3 = t; int u = bi2; bi2 = bi3; bi3 = u; }
            if (bd2 < bd1) { float t = bd1; bd1 = bd2; bd2 = t; int u = bi1; bi1 = bi2; bi2 = u; }
            if (bd1 < bd0) { float t = bd0; bd0 = bd1; bd1 = t; int u = bi0; bi0 = bi1; bi1 = u; }
        }
    }
    int* op = idxOut + ((size_t)b * NPTS + n) * KNN;
    op[0] = bi0; op[1] = bi1; op[2] = bi2; op[3] = bi3; op[4] = bi4;
}

// ---------------- fused mr-layer GEMM, scalarized (r6) ----------------
__global__ __launch_bounds__(256) void mr_gemm_s(const float* __restrict__ xt,
                                                 const int* __restrict__ idx,
                                                 const float* __restrict__ W,
                                                 const float* __restrict__ bias,
                                                 float* __restrict__ C) {
    __shared__ float As[8][128];
    __shared__ float Bs[8][128];
    const int tid = threadIdx.x;
    const int bm = blockIdx.y * 128;
    const int bn = blockIdx.x * 128;
    const int lr = tid >> 1;
    const int lc = (tid & 1) * 4;
    const int pr   = bm + lr;
    const int base = pr & ~(NPTS - 1);
    const int* ip  = idx + (size_t)pr * KNN;
    const float* xr = xt + (size_t)pr * CH;
    const float* g0 = xt + (size_t)(base + ip[0]) * CH;
    const float* g1 = xt + (size_t)(base + ip[1]) * CH;
    const float* g2 = xt + (size_t)(base + ip[2]) * CH;
    const float* g3 = xt + (size_t)(base + ip[3]) * CH;
    const float* g4 = xt + (size_t)(base + ip[4]) * CH;
    const float* Bp = W + (size_t)(bn + lr) * (2 * CH) + lc;
    const int ty = tid >> 4, tx = tid & 15;
    float acc[8][8];
#pragma unroll
    for (int i = 0; i < 8; ++i)
#pragma unroll
        for (int j = 0; j < 8; ++j) acc[i][j] = 0.0f;

    for (int k0 = 0; k0 < 2 * CH; k0 += 8) {
        const int c = (k0 + lc) >> 1;
        float x0 = xr[c],     x1 = xr[c + 1];
        float m0 = fmaxf(fmaxf(fmaxf(g0[c], g1[c]), fmaxf(g2[c], g3[c])), g4[c]) - x0;
        float m1 = fmaxf(fmaxf(fmaxf(g0[c+1], g1[c+1]), fmaxf(g2[c+1], g3[c+1])), g4[c+1]) - x1;
        float w0 = Bp[k0], w1 = Bp[k0 + 1], w2 = Bp[k0 + 2], w3 = Bp[k0 + 3];
        __syncthreads();
        As[lc + 0][lr] = x0; As[lc + 1][lr] = m0;
        As[lc + 2][lr] = x1; As[lc + 3][lr] = m1;
        Bs[lc + 0][lr] = w0; Bs[lc + 1][lr] = w1;
        Bs[lc + 2][lr] = w2; Bs[lc + 3][lr] = w3;
        __syncthreads();
#pragma unroll
        for (int k = 0; k < 8; ++k) {
#pragma unroll
            for (int i = 0; i < 8; ++i) {
                float av = As[k][ty * 8 + i];
#pragma unroll
                for (int j = 0; j < 8; ++j)
                    acc[i][j] += av * Bs[k][tx * 8 + j];
            }
        }
    }
#pragma unroll
    for (int i = 0; i < 8; ++i) {
        float* Crow = C + (size_t)(bm + ty * 8 + i) * CH + bn + tx * 8;
#pragma unroll
        for (int j = 0; j < 8; ++j)
            Crow[j] = acc[i][j] + bias[bn + tx * 8 + j];
    }
}

// ---------------- BN stats stage 1: deterministic f32 partials ----------------
__global__ __launch_bounds__(256) void stats1_kernel(const float* __restrict__ y,
                                                     float* __restrict__ psum,
                                                     float* __restrict__ psq) {
    const int q = blockIdx.x;            // 0..127
    const int t = threadIdx.x;
    const float* yp = y + (size_t)q * 128 * CH;
#pragma unroll
    for (int half = 0; half < 2; ++half) {
        int c = t + half * 256;
        float s = 0.0f, sq = 0.0f;
        for (int r = 0; r < 128; ++r) {
            float v = yp[(size_t)r * CH + c];
            s += v; sq += v * v;
        }
        psum[(size_t)q * CH + c] = s;
        psq [(size_t)q * CH + c] = sq;
    }
}

// ---------------- BN stats stage 2: deterministic final reduce ----------------
__global__ __launch_bounds__(256) void stats2_kernel(const float* __restrict__ psum,
                                                     const float* __restrict__ psq,
                                                     float* __restrict__ mv) {
    int c = blockIdx.x * 256 + threadIdx.x;   // 0..511
    float s = 0.0f, sq = 0.0f;
    for (int q = 0; q < 128; ++q) {
        s  += psum[(size_t)q * CH + c];
        sq += psq [(size_t)q * CH + c];
    }
    float mean = s * (1.0f / 16384.0f);
    float var  = sq * (1.0f / 16384.0f) - mean * mean;
    mv[c]      = mean;
    mv[CH + c] = 1.0f / sqrtf(var + 1e-5f);
}

// ---------------- y = relu(((y - mean) * rs) * g + be) ----------------
__global__ __launch_bounds__(256) void bnorm_relu_kernel(float* __restrict__ y,
                                                         const float* __restrict__ mv,
                                                         const float* __restrict__ g,
                                                         const float* __restrict__ be) {
    size_t i = (size_t)blockIdx.x * 256 + threadIdx.x;
    int c = (int)(i & (CH - 1));
    float v = y[i];
    v = ((v - mv[c]) * mv[CH + c]) * g[c] + be[c];
    y[i] = fmaxf(v, 0.0f);
}

// ---------------- head stage 1 ----------------
__global__ __launch_bounds__(256) void head1_kernel(const float* __restrict__ xt,
                                                    const float* __restrict__ Wc1,
                                                    const float* __restrict__ bc1,
                                                    float* __restrict__ h) {
    const int p = blockIdx.x;
    const int o = threadIdx.x;
    const float* xp = xt + (size_t)p * CH;
    const float* wp = Wc1 + (size_t)o * CH;
    float acc = 0.0f;
    for (int f = 0; f < CH; ++f) acc += xp[f] * wp[f];
    h[(size_t)p * 256 + o] = fmaxf(acc + bc1[o], 0.0f);
}

// ---------------- head stage 2 ----------------
__global__ __launch_bounds__(64) void head2s_kernel(const float* __restrict__ h,
                                                    const float* __restrict__ Wc2,
                                                    const float* __restrict__ bc2,
                                                    float* __restrict__ out) {
    __shared__ float red[5][64];
    const int p = blockIdx.x;
    const int t = threadIdx.x;
    const float* hp = h + (size_t)p * 256;
    float acc[5] = {0.f, 0.f, 0.f, 0.f, 0.f};
#pragma unroll
    for (int fo = 0; fo < 4; ++fo) {
        int f = t + fo * 64;
        float hv = hp[f];
#pragma unroll
        for (int j = 0; j < 5; ++j) acc[j] += hv * Wc2[j * 256 + f];
    }
#pragma unroll
    for (int j = 0; j < 5; ++j) red[j][t] = acc[j];
    __syncthreads();
    if (t == 0) {
#pragma unroll
        for (int j = 0; j < 5; ++j) {
            float s = 0.0f;
            for (int l = 0; l < 64; ++l) s += red[j][l];
            out[(size_t)p * 5 + j] = s + bc2[j];
        }
    }
}

extern "C" void kernel_launch(void* const* d_in, const int* in_sizes, int n_in,
                              void* d_out, int out_size, void* d_ws, size_t ws_size,
                              hipStream_t stream) {
    const float* x   = (const float*)d_in[0];
    const float* pos = (const float*)d_in[1];
    const float* W[3]  = {(const float*)d_in[2], (const float*)d_in[6], (const float*)d_in[10]};
    const float* bb[3] = {(const float*)d_in[3], (const float*)d_in[7], (const float*)d_in[11]};
    const float* gg[3] = {(const float*)d_in[4], (const float*)d_in[8], (const float*)d_in[12]};
    const float* be[3] = {(const float*)d_in[5], (const float*)d_in[9], (const float*)d_in[13]};
    const float* Wc1 = (const float*)d_in[14];
    const float* bc1 = (const float*)d_in[15];
    const float* Wc2 = (const float*)d_in[16];
    const float* bc2 = (const float*)d_in[17];
    float* out = (float*)d_out;

    const size_t SZ_XT = (size_t)TOT * CH * 4;               // 32 MiB each
    char* ws = (char*)d_ws;
    float* xtA  = (float*)(ws);
    float* xtB  = (float*)(ws + SZ_XT);
    int*   idxB = (int*)  (ws + 2 * SZ_XT);                  // 320 KiB
    float* psum = (float*)(ws + 2 * SZ_XT + 0x50000);        // 256 KiB
    float* psq  = psum + 128 * CH;                           // 256 KiB
    float* mv   = psq  + 128 * CH;                           // 4 KiB

    transpose_naive<<<dim3(TOT), 256, 0, stream>>>(x, xtA);
    knn_kernel<<<dim3(NB * 16), 256, 0, stream>>>(pos, idxB);

    float* cur = xtA;
    float* nxt = xtB;
    for (int blk = 0; blk < 3; ++blk) {
        mr_gemm_s<<<dim3(CH / 128, TOT / 128), 256, 0, stream>>>(cur, idxB, W[blk], bb[blk], nxt);
        stats1_kernel<<<dim3(TOT / 128), 256, 0, stream>>>(nxt, psum, psq);
        stats2_kernel<<<dim3(2), 256, 0, stream>>>(psum, psq, mv);
        bnorm_relu_kernel<<<dim3((size_t)TOT * CH / 256), 256, 0, stream>>>(nxt, mv, gg[blk], be[blk]);
        float* t = cur; cur = nxt; nxt = t;
    }
    float* h = nxt;   // after 3 swaps: cur = xtB, nxt = xtA (free)
    head1_kernel<<<dim3(TOT), 256, 0, stream>>>(cur, Wc1, bc1, h);
    head2s_kernel<<<dim3(TOT), 64, 0, stream>>>(h, Wc2, bc2, out);
}

// Round 15
// 1486.919 us; speedup vs baseline: 1.5966x; 1.5966x over previous
//
#include <hip/hip_runtime.h>

#define NPTS 4096
#define NB   4
#define CH   512
#define TOT  (NB * NPTS)   // 16384
#define KNN  5

// ---------------- transpose (LDS-tiled): x [B,C,N] -> xt [B*N, C] ----------------
__global__ __launch_bounds__(256) void transpose_kernel(const float* __restrict__ x,
                                                        float* __restrict__ xt) {
    __shared__ float tile[32][33];
    int b  = blockIdx.z;
    int n0 = blockIdx.x * 32, c0 = blockIdx.y * 32;
    int tx = threadIdx.x & 31, ty = threadIdx.x >> 5;   // ty 0..7
    const float* xp = x + ((size_t)b * CH + c0) * NPTS + n0;
#pragma unroll
    for (int i = 0; i < 32; i += 8)
        tile[ty + i][tx] = xp[(size_t)(ty + i) * NPTS + tx];
    __syncthreads();
    float* xo = xt + ((size_t)b * NPTS + n0) * CH + c0;
#pragma unroll
    for (int i = 0; i < 32; i += 8)
        xo[(size_t)(ty + i) * CH + tx] = tile[tx][ty + i];
}

// ---------------- KNN: FROZEN (r14, bit-exact vs reference) ----------------
// d2 = fl(fl(x*x)+fl(y*y)); dot = fma(y_n,y_m, fl(x_n*x_m)); dist = fl(fl(d2n+d2m)-fl(2*dot))
__global__ __launch_bounds__(256) void knn_kernel(const float* __restrict__ pos,
                                                  int* __restrict__ idxOut) {
#pragma clang fp contract(off)
    __shared__ float cx[NPTS];
    __shared__ float cy[NPTS];
    __shared__ float d2s[NPTS];
    const int b = blockIdx.x >> 4;
    const int n = ((blockIdx.x & 15) << 8) + threadIdx.x;
    const float2* P = (const float2*)(pos + (size_t)b * NPTS * 2);
    for (int m = threadIdx.x; m < NPTS; m += 256) {
        float2 c = P[m];
        cx[m] = c.x; cy[m] = c.y;
        float xx = c.x * c.x;
        float yy = c.y * c.y;
        d2s[m] = xx + yy;
    }
    __syncthreads();
    const float xq = cx[n], yq = cy[n], d2q = d2s[n];
    float bd0 = 3.4e38f, bd1 = 3.4e38f, bd2 = 3.4e38f, bd3 = 3.4e38f, bd4 = 3.4e38f;
    int   bi0 = 0, bi1 = 0, bi2 = 0, bi3 = 0, bi4 = 0;
    for (int m = 0; m < NPTS; ++m) {
        float px  = xq * cx[m];
        float dot = __builtin_fmaf(yq, cy[m], px);
        float s   = d2q + d2s[m];
        float t2  = 2.0f * dot;
        float dist = s - t2;
        if (dist < bd4) {
            bd4 = dist; bi4 = m;
            if (bd4 < bd3) { float t = bd3; bd3 = bd4; bd4 = t; int u = bi3; bi3 = bi4; bi4 = u; }
            if (bd3 < bd2) { float t = bd2; bd2 = bd3; bd3 = t; int u = bi2; bi2 = bi3; bi3 = u; }
            if (bd2 < bd1) { float t = bd1; bd1 = bd2; bd2 = t; int u = bi1; bi1 = bi2; bi2 = u; }
            if (bd1 < bd0) { float t = bd0; bd0 = bd1; bd1 = t; int u = bi0; bi0 = bi1; bi1 = u; }
        }
    }
    int* op = idxOut + ((size_t)b * NPTS + n) * KNN;
    op[0] = bi0; op[1] = bi1; op[2] = bi2; op[3] = bi3; op[4] = bi4;
}

// ---------------- fused mr-layer GEMM, vectorized (r2/r3 proven) ----------------
__global__ __launch_bounds__(256) void mr_gemm(const float* __restrict__ xt,
                                               const int* __restrict__ idx,
                                               const float* __restrict__ W,
                                               const float* __restrict__ bias,
                                               float* __restrict__ C) {
    __shared__ float As[8][128];
    __shared__ float Bs[8][128];
    const int tid = threadIdx.x;
    const int bm = blockIdx.y * 128;
    const int bn = blockIdx.x * 128;
    const int lr = tid >> 1;
    const int lc = (tid & 1) * 4;
    const int pr   = bm + lr;
    const int base = pr & ~(NPTS - 1);
    const int* ip  = idx + (size_t)pr * KNN;
    const float* xr = xt + (size_t)pr * CH;
    const float* g0 = xt + (size_t)(base + ip[0]) * CH;
    const float* g1 = xt + (size_t)(base + ip[1]) * CH;
    const float* g2 = xt + (size_t)(base + ip[2]) * CH;
    const float* g3 = xt + (size_t)(base + ip[3]) * CH;
    const float* g4 = xt + (size_t)(base + ip[4]) * CH;
    const float* Bp = W + (size_t)(bn + lr) * (2 * CH) + lc;
    const int ty = tid >> 4, tx = tid & 15;
    float acc[8][8] = {};
    for (int k0 = 0; k0 < 2 * CH; k0 += 8) {
        const int c = (k0 + lc) >> 1;
        float2 xv = *(const float2*)(xr + c);
        float2 v0 = *(const float2*)(g0 + c);
        float2 v1 = *(const float2*)(g1 + c);
        float2 v2 = *(const float2*)(g2 + c);
        float2 v3 = *(const float2*)(g3 + c);
        float2 v4 = *(const float2*)(g4 + c);
        float mx = fmaxf(fmaxf(fmaxf(v0.x, v1.x), fmaxf(v2.x, v3.x)), v4.x) - xv.x;
        float my = fmaxf(fmaxf(fmaxf(v0.y, v1.y), fmaxf(v2.y, v3.y)), v4.y) - xv.y;
        float4 bv = *(const float4*)(Bp + k0);
        __syncthreads();
        As[lc + 0][lr] = xv.x; As[lc + 1][lr] = mx;
        As[lc + 2][lr] = xv.y; As[lc + 3][lr] = my;
        Bs[lc + 0][lr] = bv.x; Bs[lc + 1][lr] = bv.y;
        Bs[lc + 2][lr] = bv.z; Bs[lc + 3][lr] = bv.w;
        __syncthreads();
#pragma unroll
        for (int k = 0; k < 8; ++k) {
            float4 a0 = *(const float4*)&As[k][ty * 8];
            float4 a1 = *(const float4*)&As[k][ty * 8 + 4];
            float4 b0 = *(const float4*)&Bs[k][tx * 8];
            float4 b1 = *(const float4*)&Bs[k][tx * 8 + 4];
            float a[8] = {a0.x, a0.y, a0.z, a0.w, a1.x, a1.y, a1.z, a1.w};
            float b[8] = {b0.x, b0.y, b0.z, b0.w, b1.x, b1.y, b1.z, b1.w};
#pragma unroll
            for (int i = 0; i < 8; ++i)
#pragma unroll
                for (int j = 0; j < 8; ++j)
                    acc[i][j] += a[i] * b[j];
        }
    }
    float bs[8];
#pragma unroll
    for (int j = 0; j < 8; ++j) bs[j] = bias[bn + tx * 8 + j];
#pragma unroll
    for (int i = 0; i < 8; ++i) {
        float* Crow = C + (size_t)(bm + ty * 8 + i) * CH + bn + tx * 8;
        float v[8];
#pragma unroll
        for (int j = 0; j < 8; ++j) v[j] = acc[i][j] + bs[j];
        *(float4*)(Crow)     = make_float4(v[0], v[1], v[2], v[3]);
        *(float4*)(Crow + 4) = make_float4(v[4], v[5], v[6], v[7]);
    }
}

// ---------------- plain tiled GEMM (head stage 1): C = A @ B^T + bias, relu ----------------
template <bool RELU>
__global__ __launch_bounds__(256) void gemm_tn(const float* __restrict__ A,
                                               const float* __restrict__ B,
                                               const float* __restrict__ bias,
                                               float* __restrict__ C,
                                               int M, int N, int Kd) {
    __shared__ float As[8][128];
    __shared__ float Bs[8][128];
    const int tid = threadIdx.x;
    const int bm = blockIdx.y * 128;
    const int bn = blockIdx.x * 128;
    const int lr = tid >> 1;
    const int lc = (tid & 1) * 4;
    const float* Ap = A + (size_t)(bm + lr) * Kd + lc;
    const float* Bp = B + (size_t)(bn + lr) * Kd + lc;
    const int ty = tid >> 4, tx = tid & 15;
    float acc[8][8] = {};
    for (int k0 = 0; k0 < Kd; k0 += 8) {
        float4 av = *(const float4*)(Ap + k0);
        float4 bv = *(const float4*)(Bp + k0);
        __syncthreads();
        As[lc + 0][lr] = av.x; As[lc + 1][lr] = av.y; As[lc + 2][lr] = av.z; As[lc + 3][lr] = av.w;
        Bs[lc + 0][lr] = bv.x; Bs[lc + 1][lr] = bv.y; Bs[lc + 2][lr] = bv.z; Bs[lc + 3][lr] = bv.w;
        __syncthreads();
#pragma unroll
        for (int k = 0; k < 8; ++k) {
            float4 a0 = *(const float4*)&As[k][ty * 8];
            float4 a1 = *(const float4*)&As[k][ty * 8 + 4];
            float4 b0 = *(const float4*)&Bs[k][tx * 8];
            float4 b1 = *(const float4*)&Bs[k][tx * 8 + 4];
            float a[8] = {a0.x, a0.y, a0.z, a0.w, a1.x, a1.y, a1.z, a1.w};
            float b[8] = {b0.x, b0.y, b0.z, b0.w, b1.x, b1.y, b1.z, b1.w};
#pragma unroll
            for (int i = 0; i < 8; ++i)
#pragma unroll
                for (int j = 0; j < 8; ++j)
                    acc[i][j] += a[i] * b[j];
        }
    }
    float bs[8];
#pragma unroll
    for (int j = 0; j < 8; ++j) bs[j] = bias[bn + tx * 8 + j];
#pragma unroll
    for (int i = 0; i < 8; ++i) {
        size_t row = (size_t)(bm + ty * 8 + i);
        float* Crow = C + row * N + bn + tx * 8;
        float v[8];
#pragma unroll
        for (int j = 0; j < 8; ++j) {
            v[j] = acc[i][j] + bs[j];
            if (RELU) v[j] = fmaxf(v[j], 0.0f);
        }
        *(float4*)(Crow)     = make_float4(v[0], v[1], v[2], v[3]);
        *(float4*)(Crow + 4) = make_float4(v[4], v[5], v[6], v[7]);
    }
}

// ---------------- BN stats stage 1: deterministic f32 partials ----------------
__global__ __launch_bounds__(256) void stats1_kernel(const float* __restrict__ y,
                                                     float* __restrict__ psum,
                                                     float* __restrict__ psq) {
    const int q = blockIdx.x;            // 0..127
    const int t = threadIdx.x;
    const float* yp = y + (size_t)q * 128 * CH;
#pragma unroll
    for (int half = 0; half < 2; ++half) {
        int c = t + half * 256;
        float s = 0.0f, sq = 0.0f;
        for (int r = 0; r < 128; ++r) {
            float v = yp[(size_t)r * CH + c];
            s += v; sq += v * v;
        }
        psum[(size_t)q * CH + c] = s;
        psq [(size_t)q * CH + c] = sq;
    }
}

// ---------------- BN stats stage 2 ----------------
__global__ __launch_bounds__(256) void stats2_kernel(const float* __restrict__ psum,
                                                     const float* __restrict__ psq,
                                                     float* __restrict__ mv) {
    int c = blockIdx.x * 256 + threadIdx.x;   // 0..511
    float s = 0.0f, sq = 0.0f;
    for (int q = 0; q < 128; ++q) {
        s  += psum[(size_t)q * CH + c];
        sq += psq [(size_t)q * CH + c];
    }
    float mean = s * (1.0f / 16384.0f);
    float var  = sq * (1.0f / 16384.0f) - mean * mean;
    mv[c]      = mean;
    mv[CH + c] = 1.0f / sqrtf(var + 1e-5f);
}

// ---------------- y = relu(((y - mean) * rs) * g + be) ----------------
__global__ __launch_bounds__(256) void bnorm_relu_kernel(float* __restrict__ y,
                                                         const float* __restrict__ mv,
                                                         const float* __restrict__ g,
                                                         const float* __restrict__ be) {
    size_t i = (size_t)blockIdx.x * 256 + threadIdx.x;
    int c = (int)(i & (CH - 1));
    float v = y[i];
    v = ((v - mv[c]) * mv[CH + c]) * g[c] + be[c];
    y[i] = fmaxf(v, 0.0f);
}

// ---------------- head stage 2 (r1 shuffle version) ----------------
__global__ __launch_bounds__(256) void head2_kernel(const float* __restrict__ h,
                                                    const float* __restrict__ Wc2,
                                                    const float* __restrict__ bc2,
                                                    float* __restrict__ out) {
    const int wave = threadIdx.x >> 6, lane = threadIdx.x & 63;
    const int p = blockIdx.x * 4 + wave;
    const float* hp = h + (size_t)p * 256;
    float acc[5] = {0.f, 0.f, 0.f, 0.f, 0.f};
#pragma unroll
    for (int fo = 0; fo < 4; ++fo) {
        int f = lane + fo * 64;
        float hv = hp[f];
#pragma unroll
        for (int j = 0; j < 5; ++j) acc[j] += hv * Wc2[j * 256 + f];
    }
#pragma unroll
    for (int j = 0; j < 5; ++j)
#pragma unroll
        for (int off = 32; off; off >>= 1) acc[j] += __shfl_down(acc[j], off);
    if (lane == 0) {
#pragma unroll
        for (int j = 0; j < 5; ++j) out[(size_t)p * 5 + j] = acc[j] + bc2[j];
    }
}

extern "C" void kernel_launch(void* const* d_in, const int* in_sizes, int n_in,
                              void* d_out, int out_size, void* d_ws, size_t ws_size,
                              hipStream_t stream) {
    const float* x   = (const float*)d_in[0];
    const float* pos = (const float*)d_in[1];
    const float* W[3]  = {(const float*)d_in[2], (const float*)d_in[6], (const float*)d_in[10]};
    const float* bb[3] = {(const float*)d_in[3], (const float*)d_in[7], (const float*)d_in[11]};
    const float* gg[3] = {(const float*)d_in[4], (const float*)d_in[8], (const float*)d_in[12]};
    const float* be[3] = {(const float*)d_in[5], (const float*)d_in[9], (const float*)d_in[13]};
    const float* Wc1 = (const float*)d_in[14];
    const float* bc1 = (const float*)d_in[15];
    const float* Wc2 = (const float*)d_in[16];
    const float* bc2 = (const float*)d_in[17];
    float* out = (float*)d_out;

    const size_t SZ_XT = (size_t)TOT * CH * 4;               // 32 MiB each
    char* ws = (char*)d_ws;
    float* xtA  = (float*)(ws);
    float* xtB  = (float*)(ws + SZ_XT);
    int*   idxB = (int*)  (ws + 2 * SZ_XT);                  // 320 KiB
    float* psum = (float*)(ws + 2 * SZ_XT + 0x50000);        // 256 KiB
    float* psq  = psum + 128 * CH;                           // 256 KiB
    float* mv   = psq  + 128 * CH;                           // 4 KiB

    transpose_kernel<<<dim3(NPTS / 32, CH / 32, NB), 256, 0, stream>>>(x, xtA);
    knn_kernel<<<dim3(NB * 16), 256, 0, stream>>>(pos, idxB);

    float* cur = xtA;
    float* nxt = xtB;
    for (int blk = 0; blk < 3; ++blk) {
        mr_gemm<<<dim3(CH / 128, TOT / 128), 256, 0, stream>>>(cur, idxB, W[blk], bb[blk], nxt);
        stats1_kernel<<<dim3(TOT / 128), 256, 0, stream>>>(nxt, psum, psq);
        stats2_kernel<<<dim3(2), 256, 0, stream>>>(psum, psq, mv);
        bnorm_relu_kernel<<<dim3((size_t)TOT * CH / 256), 256, 0, stream>>>(nxt, mv, gg[blk], be[blk]);
        float* t = cur; cur = nxt; nxt = t;
    }
    float* h = nxt;   // after 3 swaps: cur = xtB, nxt = xtA (free)
    gemm_tn<true><<<dim3(256 / 128, TOT / 128), 256, 0, stream>>>(cur, Wc1, bc1, h,
                                                                  TOT, 256, CH);
    head2_kernel<<<dim3(TOT / 4), 256, 0, stream>>>(h, Wc2, bc2, out);
}

// Round 16
// 1189.850 us; speedup vs baseline: 1.9952x; 1.2497x over previous
//
#include <hip/hip_runtime.h>

#define NPTS 4096
#define NB   4
#define CH   512
#define TOT  (NB * NPTS)   // 16384
#define KNN  5

// ---------------- transpose (LDS-tiled): x [B,C,N] -> xt [B*N, C] ----------------
__global__ __launch_bounds__(256) void transpose_kernel(const float* __restrict__ x,
                                                        float* __restrict__ xt) {
    __shared__ float tile[32][33];
    int b  = blockIdx.z;
    int n0 = blockIdx.x * 32, c0 = blockIdx.y * 32;
    int tx = threadIdx.x & 31, ty = threadIdx.x >> 5;   // ty 0..7
    const float* xp = x + ((size_t)b * CH + c0) * NPTS + n0;
#pragma unroll
    for (int i = 0; i < 32; i += 8)
        tile[ty + i][tx] = xp[(size_t)(ty + i) * NPTS + tx];
    __syncthreads();
    float* xo = xt + ((size_t)b * NPTS + n0) * CH + c0;
#pragma unroll
    for (int i = 0; i < 32; i += 8)
        xo[(size_t)(ty + i) * CH + tx] = tile[tx][ty + i];
}

// ---------------- KNN: frozen r14 arithmetic, 4-way parallel scan + exact merge ----------------
// dist formula bit-identical to r14 (contract off, SOP d2, single-FMA dot).
// Block = 64 queries x 4 waves; wave w scans m in [w*1024,(w+1)*1024) with the same
// strict-< ascending-m insertion; merge processes (w asc, j asc) with strict-< =>
// provably identical selection to the sequential scan.
__global__ __launch_bounds__(256) void knn_kernel(const float* __restrict__ pos,
                                                  int* __restrict__ idxOut) {
#pragma clang fp contract(off)
    __shared__ float cx[NPTS];
    __shared__ float cy[NPTS];
    __shared__ float d2s[NPTS];
    __shared__ float cd[4][64][KNN];
    __shared__ int   ci[4][64][KNN];
    const int b  = blockIdx.x >> 6;              // 64 blocks per batch
    const int q0 = (blockIdx.x & 63) << 6;       // 64 queries per block
    const int wv = threadIdx.x >> 6;             // 0..3
    const int ln = threadIdx.x & 63;
    const int n  = q0 + ln;                      // query within batch
    const float2* P = (const float2*)(pos + (size_t)b * NPTS * 2);
    for (int m = threadIdx.x; m < NPTS; m += 256) {
        float2 c = P[m];
        cx[m] = c.x; cy[m] = c.y;
        float xx = c.x * c.x;
        float yy = c.y * c.y;
        d2s[m] = xx + yy;
    }
    __syncthreads();
    const float xq = cx[n], yq = cy[n], d2q = d2s[n];
    float bd0 = 3.4e38f, bd1 = 3.4e38f, bd2 = 3.4e38f, bd3 = 3.4e38f, bd4 = 3.4e38f;
    int   bi0 = 0, bi1 = 0, bi2 = 0, bi3 = 0, bi4 = 0;
    const int m0 = wv << 10, m1 = m0 + 1024;
    for (int m = m0; m < m1; m += 4) {
        float dist[4];
#pragma unroll
        for (int u = 0; u < 4; ++u) {
            float px  = xq * cx[m + u];
            float dot = __builtin_fmaf(yq, cy[m + u], px);
            float s   = d2q + d2s[m + u];
            float t2  = 2.0f * dot;
            dist[u] = s - t2;
        }
        float mn = fminf(fminf(dist[0], dist[1]), fminf(dist[2], dist[3]));
        if (mn < bd4) {
#pragma unroll
            for (int u = 0; u < 4; ++u) {
                float d = dist[u];
                if (d < bd4) {
                    bd4 = d; bi4 = m + u;
                    if (bd4 < bd3) { float t = bd3; bd3 = bd4; bd4 = t; int v = bi3; bi3 = bi4; bi4 = v; }
                    if (bd3 < bd2) { float t = bd2; bd2 = bd3; bd3 = t; int v = bi2; bi2 = bi3; bi3 = v; }
                    if (bd2 < bd1) { float t = bd1; bd1 = bd2; bd2 = t; int v = bi1; bi1 = bi2; bi2 = v; }
                    if (bd1 < bd0) { float t = bd0; bd0 = bd1; bd1 = t; int v = bi0; bi0 = bi1; bi1 = v; }
                }
            }
        }
    }
    cd[wv][ln][0] = bd0; cd[wv][ln][1] = bd1; cd[wv][ln][2] = bd2; cd[wv][ln][3] = bd3; cd[wv][ln][4] = bd4;
    ci[wv][ln][0] = bi0; ci[wv][ln][1] = bi1; ci[wv][ln][2] = bi2; ci[wv][ln][3] = bi3; ci[wv][ln][4] = bi4;
    __syncthreads();
    if (wv == 0) {
        float md0 = 3.4e38f, md1 = 3.4e38f, md2 = 3.4e38f, md3 = 3.4e38f, md4 = 3.4e38f;
        int   mi0 = 0, mi1 = 0, mi2 = 0, mi3 = 0, mi4 = 0;
#pragma unroll
        for (int w = 0; w < 4; ++w) {
#pragma unroll
            for (int j = 0; j < KNN; ++j) {
                float d = cd[w][ln][j];
                int   id = ci[w][ln][j];
                if (d < md4) {
                    md4 = d; mi4 = id;
                    if (md4 < md3) { float t = md3; md3 = md4; md4 = t; int v = mi3; mi3 = mi4; mi4 = v; }
                    if (md3 < md2) { float t = md2; md2 = md3; md3 = t; int v = mi2; mi2 = mi3; mi3 = v; }
                    if (md2 < md1) { float t = md1; md1 = md2; md2 = t; int v = mi1; mi1 = mi2; mi2 = v; }
                    if (md1 < md0) { float t = md0; md0 = md1; md1 = t; int v = mi0; mi0 = mi1; mi1 = v; }
                }
            }
        }
        int* op = idxOut + ((size_t)b * NPTS + n) * KNN;
        op[0] = mi0; op[1] = mi1; op[2] = mi2; op[3] = mi3; op[4] = mi4;
    }
}

// ---------------- fused mr-layer GEMM, vectorized (r15 proven) ----------------
__global__ __launch_bounds__(256) void mr_gemm(const float* __restrict__ xt,
                                               const int* __restrict__ idx,
                                               const float* __restrict__ W,
                                               const float* __restrict__ bias,
                                               float* __restrict__ C) {
    __shared__ float As[8][128];
    __shared__ float Bs[8][128];
    const int tid = threadIdx.x;
    const int bm = blockIdx.y * 128;
    const int bn = blockIdx.x * 128;
    const int lr = tid >> 1;
    const int lc = (tid & 1) * 4;
    const int pr   = bm + lr;
    const int base = pr & ~(NPTS - 1);
    const int* ip  = idx + (size_t)pr * KNN;
    const float* xr = xt + (size_t)pr * CH;
    const float* g0 = xt + (size_t)(base + ip[0]) * CH;
    const float* g1 = xt + (size_t)(base + ip[1]) * CH;
    const float* g2 = xt + (size_t)(base + ip[2]) * CH;
    const float* g3 = xt + (size_t)(base + ip[3]) * CH;
    const float* g4 = xt + (size_t)(base + ip[4]) * CH;
    const float* Bp = W + (size_t)(bn + lr) * (2 * CH) + lc;
    const int ty = tid >> 4, tx = tid & 15;
    float acc[8][8] = {};
    for (int k0 = 0; k0 < 2 * CH; k0 += 8) {
        const int c = (k0 + lc) >> 1;
        float2 xv = *(const float2*)(xr + c);
        float2 v0 = *(const float2*)(g0 + c);
        float2 v1 = *(const float2*)(g1 + c);
        float2 v2 = *(const float2*)(g2 + c);
        float2 v3 = *(const float2*)(g3 + c);
        float2 v4 = *(const float2*)(g4 + c);
        float mx = fmaxf(fmaxf(fmaxf(v0.x, v1.x), fmaxf(v2.x, v3.x)), v4.x) - xv.x;
        float my = fmaxf(fmaxf(fmaxf(v0.y, v1.y), fmaxf(v2.y, v3.y)), v4.y) - xv.y;
        float4 bv = *(const float4*)(Bp + k0);
        __syncthreads();
        As[lc + 0][lr] = xv.x; As[lc + 1][lr] = mx;
        As[lc + 2][lr] = xv.y; As[lc + 3][lr] = my;
        Bs[lc + 0][lr] = bv.x; Bs[lc + 1][lr] = bv.y;
        Bs[lc + 2][lr] = bv.z; Bs[lc + 3][lr] = bv.w;
        __syncthreads();
#pragma unroll
        for (int k = 0; k < 8; ++k) {
            float4 a0 = *(const float4*)&As[k][ty * 8];
            float4 a1 = *(const float4*)&As[k][ty * 8 + 4];
            float4 b0 = *(const float4*)&Bs[k][tx * 8];
            float4 b1 = *(const float4*)&Bs[k][tx * 8 + 4];
            float a[8] = {a0.x, a0.y, a0.z, a0.w, a1.x, a1.y, a1.z, a1.w};
            float b[8] = {b0.x, b0.y, b0.z, b0.w, b1.x, b1.y, b1.z, b1.w};
#pragma unroll
            for (int i = 0; i < 8; ++i)
#pragma unroll
                for (int j = 0; j < 8; ++j)
                    acc[i][j] += a[i] * b[j];
        }
    }
    float bs[8];
#pragma unroll
    for (int j = 0; j < 8; ++j) bs[j] = bias[bn + tx * 8 + j];
#pragma unroll
    for (int i = 0; i < 8; ++i) {
        float* Crow = C + (size_t)(bm + ty * 8 + i) * CH + bn + tx * 8;
        float v[8];
#pragma unroll
        for (int j = 0; j < 8; ++j) v[j] = acc[i][j] + bs[j];
        *(float4*)(Crow)     = make_float4(v[0], v[1], v[2], v[3]);
        *(float4*)(Crow + 4) = make_float4(v[4], v[5], v[6], v[7]);
    }
}

// ---------------- plain tiled GEMM (head stage 1) ----------------
template <bool RELU>
__global__ __launch_bounds__(256) void gemm_tn(const float* __restrict__ A,
                                               const float* __restrict__ B,
                                               const float* __restrict__ bias,
                                               float* __restrict__ C,
                                               int M, int N, int Kd) {
    __shared__ float As[8][128];
    __shared__ float Bs[8][128];
    const int tid = threadIdx.x;
    const int bm = blockIdx.y * 128;
    const int bn = blockIdx.x * 128;
    const int lr = tid >> 1;
    const int lc = (tid & 1) * 4;
    const float* Ap = A + (size_t)(bm + lr) * Kd + lc;
    const float* Bp = B + (size_t)(bn + lr) * Kd + lc;
    const int ty = tid >> 4, tx = tid & 15;
    float acc[8][8] = {};
    for (int k0 = 0; k0 < Kd; k0 += 8) {
        float4 av = *(const float4*)(Ap + k0);
        float4 bv = *(const float4*)(Bp + k0);
        __syncthreads();
        As[lc + 0][lr] = av.x; As[lc + 1][lr] = av.y; As[lc + 2][lr] = av.z; As[lc + 3][lr] = av.w;
        Bs[lc + 0][lr] = bv.x; Bs[lc + 1][lr] = bv.y; Bs[lc + 2][lr] = bv.z; Bs[lc + 3][lr] = bv.w;
        __syncthreads();
#pragma unroll
        for (int k = 0; k < 8; ++k) {
            float4 a0 = *(const float4*)&As[k][ty * 8];
            float4 a1 = *(const float4*)&As[k][ty * 8 + 4];
            float4 b0 = *(const float4*)&Bs[k][tx * 8];
            float4 b1 = *(const float4*)&Bs[k][tx * 8 + 4];
            float a[8] = {a0.x, a0.y, a0.z, a0.w, a1.x, a1.y, a1.z, a1.w};
            float b[8] = {b0.x, b0.y, b0.z, b0.w, b1.x, b1.y, b1.z, b1.w};
#pragma unroll
            for (int i = 0; i < 8; ++i)
#pragma unroll
                for (int j = 0; j < 8; ++j)
                    acc[i][j] += a[i] * b[j];
        }
    }
    float bs[8];
#pragma unroll
    for (int j = 0; j < 8; ++j) bs[j] = bias[bn + tx * 8 + j];
#pragma unroll
    for (int i = 0; i < 8; ++i) {
        size_t row = (size_t)(bm + ty * 8 + i);
        float* Crow = C + row * N + bn + tx * 8;
        float v[8];
#pragma unroll
        for (int j = 0; j < 8; ++j) {
            v[j] = acc[i][j] + bs[j];
            if (RELU) v[j] = fmaxf(v[j], 0.0f);
        }
        *(float4*)(Crow)     = make_float4(v[0], v[1], v[2], v[3]);
        *(float4*)(Crow + 4) = make_float4(v[4], v[5], v[6], v[7]);
    }
}

// ---------------- BN stats stage 1 ----------------
__global__ __launch_bounds__(256) void stats1_kernel(const float* __restrict__ y,
                                                     float* __restrict__ psum,
                                                     float* __restrict__ psq) {
    const int q = blockIdx.x;            // 0..127
    const int t = threadIdx.x;
    const float* yp = y + (size_t)q * 128 * CH;
#pragma unroll
    for (int half = 0; half < 2; ++half) {
        int c = t + half * 256;
        float s = 0.0f, sq = 0.0f;
        for (int r = 0; r < 128; ++r) {
            float v = yp[(size_t)r * CH + c];
            s += v; sq += v * v;
        }
        psum[(size_t)q * CH + c] = s;
        psq [(size_t)q * CH + c] = sq;
    }
}

// ---------------- BN stats stage 2 ----------------
__global__ __launch_bounds__(256) void stats2_kernel(const float* __restrict__ psum,
                                                     const float* __restrict__ psq,
                                                     float* __restrict__ mv) {
    int c = blockIdx.x * 256 + threadIdx.x;   // 0..511
    float s = 0.0f, sq = 0.0f;
    for (int q = 0; q < 128; ++q) {
        s  += psum[(size_t)q * CH + c];
        sq += psq [(size_t)q * CH + c];
    }
    float mean = s * (1.0f / 16384.0f);
    float var  = sq * (1.0f / 16384.0f) - mean * mean;
    mv[c]      = mean;
    mv[CH + c] = 1.0f / sqrtf(var + 1e-5f);
}

// ---------------- y = relu(((y - mean) * rs) * g + be) ----------------
__global__ __launch_bounds__(256) void bnorm_relu_kernel(float* __restrict__ y,
                                                         const float* __restrict__ mv,
                                                         const float* __restrict__ g,
                                                         const float* __restrict__ be) {
    size_t i = (size_t)blockIdx.x * 256 + threadIdx.x;
    int c = (int)(i & (CH - 1));
    float v = y[i];
    v = ((v - mv[c]) * mv[CH + c]) * g[c] + be[c];
    y[i] = fmaxf(v, 0.0f);
}

// ---------------- head stage 2 (shuffle) ----------------
__global__ __launch_bounds__(256) void head2_kernel(const float* __restrict__ h,
                                                    const float* __restrict__ Wc2,
                                                    const float* __restrict__ bc2,
                                                    float* __restrict__ out) {
    const int wave = threadIdx.x >> 6, lane = threadIdx.x & 63;
    const int p = blockIdx.x * 4 + wave;
    const float* hp = h + (size_t)p * 256;
    float acc[5] = {0.f, 0.f, 0.f, 0.f, 0.f};
#pragma unroll
    for (int fo = 0; fo < 4; ++fo) {
        int f = lane + fo * 64;
        float hv = hp[f];
#pragma unroll
        for (int j = 0; j < 5; ++j) acc[j] += hv * Wc2[j * 256 + f];
    }
#pragma unroll
    for (int j = 0; j < 5; ++j)
#pragma unroll
        for (int off = 32; off; off >>= 1) acc[j] += __shfl_down(acc[j], off);
    if (lane == 0) {
#pragma unroll
        for (int j = 0; j < 5; ++j) out[(size_t)p * 5 + j] = acc[j] + bc2[j];
    }
}

extern "C" void kernel_launch(void* const* d_in, const int* in_sizes, int n_in,
                              void* d_out, int out_size, void* d_ws, size_t ws_size,
                              hipStream_t stream) {
    const float* x   = (const float*)d_in[0];
    const float* pos = (const float*)d_in[1];
    const float* W[3]  = {(const float*)d_in[2], (const float*)d_in[6], (const float*)d_in[10]};
    const float* bb[3] = {(const float*)d_in[3], (const float*)d_in[7], (const float*)d_in[11]};
    const float* gg[3] = {(const float*)d_in[4], (const float*)d_in[8], (const float*)d_in[12]};
    const float* be[3] = {(const float*)d_in[5], (const float*)d_in[9], (const float*)d_in[13]};
    const float* Wc1 = (const float*)d_in[14];
    const float* bc1 = (const float*)d_in[15];
    const float* Wc2 = (const float*)d_in[16];
    const float* bc2 = (const float*)d_in[17];
    float* out = (float*)d_out;

    const size_t SZ_XT = (size_t)TOT * CH * 4;               // 32 MiB each
    char* ws = (char*)d_ws;
    float* xtA  = (float*)(ws);
    float* xtB  = (float*)(ws + SZ_XT);
    int*   idxB = (int*)  (ws + 2 * SZ_XT);                  // 320 KiB
    float* psum = (float*)(ws + 2 * SZ_XT + 0x50000);        // 256 KiB
    float* psq  = psum + 128 * CH;                           // 256 KiB
    float* mv   = psq  + 128 * CH;                           // 4 KiB

    transpose_kernel<<<dim3(NPTS / 32, CH / 32, NB), 256, 0, stream>>>(x, xtA);
    knn_kernel<<<dim3(NB * 64), 256, 0, stream>>>(pos, idxB);

    float* cur = xtA;
    float* nxt = xtB;
    for (int blk = 0; blk < 3; ++blk) {
        mr_gemm<<<dim3(CH / 128, TOT / 128), 256, 0, stream>>>(cur, idxB, W[blk], bb[blk], nxt);
        stats1_kernel<<<dim3(TOT / 128), 256, 0, stream>>>(nxt, psum, psq);
        stats2_kernel<<<dim3(2), 256, 0, stream>>>(psum, psq, mv);
        bnorm_relu_kernel<<<dim3((size_t)TOT * CH / 256), 256, 0, stream>>>(nxt, mv, gg[blk], be[blk]);
        float* t = cur; cur = nxt; nxt = t;
    }
    float* h = nxt;   // after 3 swaps: cur = xtB, nxt = xtA (free)
    gemm_tn<true><<<dim3(256 / 128, TOT / 128), 256, 0, stream>>>(cur, Wc1, bc1, h,
                                                                  TOT, 256, CH);
    head2_kernel<<<dim3(TOT / 4), 256, 0, stream>>>(h, Wc2, bc2, out);
}

// Round 17
// 726.401 us; speedup vs baseline: 3.2681x; 1.6380x over previous
//
#include <hip/hip_runtime.h>

#define NPTS 4096
#define NB   4
#define CH   512
#define TOT  (NB * NPTS)   // 16384
#define KNN  5
#define BK   32

typedef _Float16 half8_t __attribute__((ext_vector_type(8)));
typedef float    f32x4   __attribute__((ext_vector_type(4)));

// ---------------- transpose (LDS-tiled): x [B,C,N] -> xt [B*N, C] ----------------
__global__ __launch_bounds__(256) void transpose_kernel(const float* __restrict__ x,
                                                        float* __restrict__ xt) {
    __shared__ float tile[32][33];
    int b  = blockIdx.z;
    int n0 = blockIdx.x * 32, c0 = blockIdx.y * 32;
    int tx = threadIdx.x & 31, ty = threadIdx.x >> 5;
    const float* xp = x + ((size_t)b * CH + c0) * NPTS + n0;
#pragma unroll
    for (int i = 0; i < 32; i += 8)
        tile[ty + i][tx] = xp[(size_t)(ty + i) * NPTS + tx];
    __syncthreads();
    float* xo = xt + ((size_t)b * NPTS + n0) * CH + c0;
#pragma unroll
    for (int i = 0; i < 32; i += 8)
        xo[(size_t)(ty + i) * CH + tx] = tile[tx][ty + i];
}

// ---------------- KNN: FROZEN (r14/r16 bit-exact, 4-way scan + exact merge) ----------------
__global__ __launch_bounds__(256) void knn_kernel(const float* __restrict__ pos,
                                                  int* __restrict__ idxOut) {
#pragma clang fp contract(off)
    __shared__ float cx[NPTS];
    __shared__ float cy[NPTS];
    __shared__ float d2s[NPTS];
    __shared__ float cd[4][64][KNN];
    __shared__ int   ci[4][64][KNN];
    const int b  = blockIdx.x >> 6;
    const int q0 = (blockIdx.x & 63) << 6;
    const int wv = threadIdx.x >> 6;
    const int ln = threadIdx.x & 63;
    const int n  = q0 + ln;
    const float2* P = (const float2*)(pos + (size_t)b * NPTS * 2);
    for (int m = threadIdx.x; m < NPTS; m += 256) {
        float2 c = P[m];
        cx[m] = c.x; cy[m] = c.y;
        float xx = c.x * c.x;
        float yy = c.y * c.y;
        d2s[m] = xx + yy;
    }
    __syncthreads();
    const float xq = cx[n], yq = cy[n], d2q = d2s[n];
    float bd0 = 3.4e38f, bd1 = 3.4e38f, bd2 = 3.4e38f, bd3 = 3.4e38f, bd4 = 3.4e38f;
    int   bi0 = 0, bi1 = 0, bi2 = 0, bi3 = 0, bi4 = 0;
    const int m0 = wv << 10, m1 = m0 + 1024;
    for (int m = m0; m < m1; m += 4) {
        float dist[4];
#pragma unroll
        for (int u = 0; u < 4; ++u) {
            float px  = xq * cx[m + u];
            float dot = __builtin_fmaf(yq, cy[m + u], px);
            float s   = d2q + d2s[m + u];
            float t2  = 2.0f * dot;
            dist[u] = s - t2;
        }
        float mn = fminf(fminf(dist[0], dist[1]), fminf(dist[2], dist[3]));
        if (mn < bd4) {
#pragma unroll
            for (int u = 0; u < 4; ++u) {
                float d = dist[u];
                if (d < bd4) {
                    bd4 = d; bi4 = m + u;
                    if (bd4 < bd3) { float t = bd3; bd3 = bd4; bd4 = t; int v = bi3; bi3 = bi4; bi4 = v; }
                    if (bd3 < bd2) { float t = bd2; bd2 = bd3; bd3 = t; int v = bi2; bi2 = bi3; bi3 = v; }
                    if (bd2 < bd1) { float t = bd1; bd1 = bd2; bd2 = t; int v = bi1; bi1 = bi2; bi2 = v; }
                    if (bd1 < bd0) { float t = bd0; bd0 = bd1; bd1 = t; int v = bi0; bi0 = bi1; bi1 = v; }
                }
            }
        }
    }
    cd[wv][ln][0] = bd0; cd[wv][ln][1] = bd1; cd[wv][ln][2] = bd2; cd[wv][ln][3] = bd3; cd[wv][ln][4] = bd4;
    ci[wv][ln][0] = bi0; ci[wv][ln][1] = bi1; ci[wv][ln][2] = bi2; ci[wv][ln][3] = bi3; ci[wv][ln][4] = bi4;
    __syncthreads();
    if (wv == 0) {
        float md0 = 3.4e38f, md1 = 3.4e38f, md2 = 3.4e38f, md3 = 3.4e38f, md4 = 3.4e38f;
        int   mi0 = 0, mi1 = 0, mi2 = 0, mi3 = 0, mi4 = 0;
#pragma unroll
        for (int w = 0; w < 4; ++w) {
#pragma unroll
            for (int j = 0; j < KNN; ++j) {
                float d = cd[w][ln][j];
                int  id = ci[w][ln][j];
                if (d < md4) {
                    md4 = d; mi4 = id;
                    if (md4 < md3) { float t = md3; md3 = md4; md4 = t; int v = mi3; mi3 = mi4; mi4 = v; }
                    if (md3 < md2) { float t = md2; md2 = md3; md3 = t; int v = mi2; mi2 = mi3; mi3 = v; }
                    if (md2 < md1) { float t = md1; md1 = md2; md2 = t; int v = mi1; mi1 = mi2; mi2 = v; }
                    if (md1 < md0) { float t = md0; md0 = md1; md1 = t; int v = mi0; mi0 = mi1; mi1 = v; }
                }
            }
        }
        int* op = idxOut + ((size_t)b * NPTS + n) * KNN;
        op[0] = mi0; op[1] = mi1; op[2] = mi2; op[3] = mi3; op[4] = mi4;
    }
}

// ---------------- fused mr-layer GEMM, f16 MFMA (f32 accumulate) ----------------
// C[p,o] = sum_f feat[p,f]*W[o,f] + bias[o];  feat interleaved [x_c, mr_c, ...] in f16.
// 128x128 tile, BK=32, 4 waves (2x2), 16x16x32 MFMA, 4x4 tiles/wave.
__global__ __launch_bounds__(256) void mr_gemm_mfma(const float* __restrict__ xt,
                                                    const int* __restrict__ idx,
                                                    const float* __restrict__ W,
                                                    const float* __restrict__ bias,
                                                    float* __restrict__ C) {
    __shared__ _Float16 As[128][BK + 8];   // 40-half rows (80 B): frag reads 2-way only
    __shared__ _Float16 Bs[128][BK + 8];
    const int tid = threadIdx.x;
    const int bm = blockIdx.y * 128;
    const int bn = blockIdx.x * 128;
    // staging role
    const int r  = tid >> 1;           // 0..127
    const int hf = tid & 1;            // 0/1 -> features hf*16..+15 (channels hf*8..+7)
    const int pr   = bm + r;
    const int base = pr & ~(NPTS - 1);
    const int* ip  = idx + (size_t)pr * KNN;
    const float* xr = xt + (size_t)pr * CH;
    const float* g0 = xt + (size_t)(base + ip[0]) * CH;
    const float* g1 = xt + (size_t)(base + ip[1]) * CH;
    const float* g2 = xt + (size_t)(base + ip[2]) * CH;
    const float* g3 = xt + (size_t)(base + ip[3]) * CH;
    const float* g4 = xt + (size_t)(base + ip[4]) * CH;
    const float* Wp = W + (size_t)(bn + r) * (2 * CH);
    // mfma role
    const int wv = tid >> 6;
    const int ln = tid & 63;
    const int wm = (wv >> 1) * 64;
    const int wn = (wv & 1) * 64;
    const int lq = ln >> 4;            // quad 0..3
    const int lc = ln & 15;

    f32x4 zero = {0.0f, 0.0f, 0.0f, 0.0f};
    f32x4 acc[4][4];
#pragma unroll
    for (int i = 0; i < 4; ++i)
#pragma unroll
        for (int j = 0; j < 4; ++j) acc[i][j] = zero;

    for (int k0 = 0; k0 < 2 * CH; k0 += BK) {
        const int cb = (k0 >> 1) + hf * 8;
        float xa[8], a0[8], a1[8], a2[8], a3[8], a4[8], wa[16];
        *(float4*)(xa)     = *(const float4*)(xr + cb);
        *(float4*)(xa + 4) = *(const float4*)(xr + cb + 4);
        *(float4*)(a0)     = *(const float4*)(g0 + cb);
        *(float4*)(a0 + 4) = *(const float4*)(g0 + cb + 4);
        *(float4*)(a1)     = *(const float4*)(g1 + cb);
        *(float4*)(a1 + 4) = *(const float4*)(g1 + cb + 4);
        *(float4*)(a2)     = *(const float4*)(g2 + cb);
        *(float4*)(a2 + 4) = *(const float4*)(g2 + cb + 4);
        *(float4*)(a3)     = *(const float4*)(g3 + cb);
        *(float4*)(a3 + 4) = *(const float4*)(g3 + cb + 4);
        *(float4*)(a4)     = *(const float4*)(g4 + cb);
        *(float4*)(a4 + 4) = *(const float4*)(g4 + cb + 4);
        *(float4*)(wa)      = *(const float4*)(Wp + k0 + hf * 16);
        *(float4*)(wa + 4)  = *(const float4*)(Wp + k0 + hf * 16 + 4);
        *(float4*)(wa + 8)  = *(const float4*)(Wp + k0 + hf * 16 + 8);
        *(float4*)(wa + 12) = *(const float4*)(Wp + k0 + hf * 16 + 12);
        union { _Float16 h[16]; float4 v[2]; } ta, tb;
#pragma unroll
        for (int j = 0; j < 8; ++j) {
            float mr = fmaxf(fmaxf(fmaxf(a0[j], a1[j]), fmaxf(a2[j], a3[j])), a4[j]) - xa[j];
            ta.h[2 * j]     = (_Float16)xa[j];
            ta.h[2 * j + 1] = (_Float16)mr;
        }
#pragma unroll
        for (int j = 0; j < 16; ++j) tb.h[j] = (_Float16)wa[j];
        __syncthreads();
        ((float4*)&As[r][hf * 16])[0] = ta.v[0];
        ((float4*)&As[r][hf * 16])[1] = ta.v[1];
        ((float4*)&Bs[r][hf * 16])[0] = tb.v[0];
        ((float4*)&Bs[r][hf * 16])[1] = tb.v[1];
        __syncthreads();
        half8_t af[4], bf[4];
#pragma unroll
        for (int mt = 0; mt < 4; ++mt)
            af[mt] = *(const half8_t*)&As[wm + mt * 16 + lc][lq * 8];
#pragma unroll
        for (int nt = 0; nt < 4; ++nt)
            bf[nt] = *(const half8_t*)&Bs[wn + nt * 16 + lc][lq * 8];
#pragma unroll
        for (int mt = 0; mt < 4; ++mt)
#pragma unroll
            for (int nt = 0; nt < 4; ++nt)
                acc[mt][nt] = __builtin_amdgcn_mfma_f32_16x16x32_f16(af[mt], bf[nt],
                                                                     acc[mt][nt], 0, 0, 0);
    }
    // epilogue: C/D layout col=lane&15, row=quad*4+reg
#pragma unroll
    for (int nt = 0; nt < 4; ++nt) {
        const int col = bn + wn + nt * 16 + lc;
        const float bv = bias[col];
#pragma unroll
        for (int mt = 0; mt < 4; ++mt) {
#pragma unroll
            for (int v = 0; v < 4; ++v) {
                const int row = bm + wm + mt * 16 + lq * 4 + v;
                C[(size_t)row * CH + col] = acc[mt][nt][v] + bv;
            }
        }
    }
}

// ---------------- plain tiled GEMM (head stage 1), fp32 ----------------
template <bool RELU>
__global__ __launch_bounds__(256) void gemm_tn(const float* __restrict__ A,
                                               const float* __restrict__ B,
                                               const float* __restrict__ bias,
                                               float* __restrict__ C,
                                               int M, int N, int Kd) {
    __shared__ float As[8][128];
    __shared__ float Bs[8][128];
    const int tid = threadIdx.x;
    const int bm = blockIdx.y * 128;
    const int bn = blockIdx.x * 128;
    const int lr = tid >> 1;
    const int lc = (tid & 1) * 4;
    const float* Ap = A + (size_t)(bm + lr) * Kd + lc;
    const float* Bp = B + (size_t)(bn + lr) * Kd + lc;
    const int ty = tid >> 4, tx = tid & 15;
    float acc[8][8] = {};
    for (int k0 = 0; k0 < Kd; k0 += 8) {
        float4 av = *(const float4*)(Ap + k0);
        float4 bv = *(const float4*)(Bp + k0);
        __syncthreads();
        As[lc + 0][lr] = av.x; As[lc + 1][lr] = av.y; As[lc + 2][lr] = av.z; As[lc + 3][lr] = av.w;
        Bs[lc + 0][lr] = bv.x; Bs[lc + 1][lr] = bv.y; Bs[lc + 2][lr] = bv.z; Bs[lc + 3][lr] = bv.w;
        __syncthreads();
#pragma unroll
        for (int k = 0; k < 8; ++k) {
            float4 a0 = *(const float4*)&As[k][ty * 8];
            float4 a1 = *(const float4*)&As[k][ty * 8 + 4];
            float4 b0 = *(const float4*)&Bs[k][tx * 8];
            float4 b1 = *(const float4*)&Bs[k][tx * 8 + 4];
            float a[8] = {a0.x, a0.y, a0.z, a0.w, a1.x, a1.y, a1.z, a1.w};
            float b[8] = {b0.x, b0.y, b0.z, b0.w, b1.x, b1.y, b1.z, b1.w};
#pragma unroll
            for (int i = 0; i < 8; ++i)
#pragma unroll
                for (int j = 0; j < 8; ++j)
                    acc[i][j] += a[i] * b[j];
        }
    }
    float bs[8];
#pragma unroll
    for (int j = 0; j < 8; ++j) bs[j] = bias[bn + tx * 8 + j];
#pragma unroll
    for (int i = 0; i < 8; ++i) {
        size_t row = (size_t)(bm + ty * 8 + i);
        float* Crow = C + row * N + bn + tx * 8;
        float v[8];
#pragma unroll
        for (int j = 0; j < 8; ++j) {
            v[j] = acc[i][j] + bs[j];
            if (RELU) v[j] = fmaxf(v[j], 0.0f);
        }
        *(float4*)(Crow)     = make_float4(v[0], v[1], v[2], v[3]);
        *(float4*)(Crow + 4) = make_float4(v[4], v[5], v[6], v[7]);
    }
}

// ---------------- BN stats stage 1 ----------------
__global__ __launch_bounds__(256) void stats1_kernel(const float* __restrict__ y,
                                                     float* __restrict__ psum,
                                                     float* __restrict__ psq) {
    const int q = blockIdx.x;
    const int t = threadIdx.x;
    const float* yp = y + (size_t)q * 128 * CH;
#pragma unroll
    for (int half = 0; half < 2; ++half) {
        int c = t + half * 256;
        float s = 0.0f, sq = 0.0f;
        for (int r = 0; r < 128; ++r) {
            float v = yp[(size_t)r * CH + c];
            s += v; sq += v * v;
        }
        psum[(size_t)q * CH + c] = s;
        psq [(size_t)q * CH + c] = sq;
    }
}

// ---------------- BN stats stage 2 ----------------
__global__ __launch_bounds__(256) void stats2_kernel(const float* __restrict__ psum,
                                                     const float* __restrict__ psq,
                                                     float* __restrict__ mv) {
    int c = blockIdx.x * 256 + threadIdx.x;
    float s = 0.0f, sq = 0.0f;
    for (int q = 0; q < 128; ++q) {
        s  += psum[(size_t)q * CH + c];
        sq += psq [(size_t)q * CH + c];
    }
    float mean = s * (1.0f / 16384.0f);
    float var  = sq * (1.0f / 16384.0f) - mean * mean;
    mv[c]      = mean;
    mv[CH + c] = 1.0f / sqrtf(var + 1e-5f);
}

// ---------------- y = relu(((y - mean) * rs) * g + be) ----------------
__global__ __launch_bounds__(256) void bnorm_relu_kernel(float* __restrict__ y,
                                                         const float* __restrict__ mv,
                                                         const float* __restrict__ g,
                                                         const float* __restrict__ be) {
    size_t i = (size_t)blockIdx.x * 256 + threadIdx.x;
    int c = (int)(i & (CH - 1));
    float v = y[i];
    v = ((v - mv[c]) * mv[CH + c]) * g[c] + be[c];
    y[i] = fmaxf(v, 0.0f);
}

// ---------------- head stage 2 (shuffle) ----------------
__global__ __launch_bounds__(256) void head2_kernel(const float* __restrict__ h,
                                                    const float* __restrict__ Wc2,
                                                    const float* __restrict__ bc2,
                                                    float* __restrict__ out) {
    const int wave = threadIdx.x >> 6, lane = threadIdx.x & 63;
    const int p = blockIdx.x * 4 + wave;
    const float* hp = h + (size_t)p * 256;
    float acc[5] = {0.f, 0.f, 0.f, 0.f, 0.f};
#pragma unroll
    for (int fo = 0; fo < 4; ++fo) {
        int f = lane + fo * 64;
        float hv = hp[f];
#pragma unroll
        for (int j = 0; j < 5; ++j) acc[j] += hv * Wc2[j * 256 + f];
    }
#pragma unroll
    for (int j = 0; j < 5; ++j)
#pragma unroll
        for (int off = 32; off; off >>= 1) acc[j] += __shfl_down(acc[j], off);
    if (lane == 0) {
#pragma unroll
        for (int j = 0; j < 5; ++j) out[(size_t)p * 5 + j] = acc[j] + bc2[j];
    }
}

extern "C" void kernel_launch(void* const* d_in, const int* in_sizes, int n_in,
                              void* d_out, int out_size, void* d_ws, size_t ws_size,
                              hipStream_t stream) {
    const float* x   = (const float*)d_in[0];
    const float* pos = (const float*)d_in[1];
    const float* W[3]  = {(const float*)d_in[2], (const float*)d_in[6], (const float*)d_in[10]};
    const float* bb[3] = {(const float*)d_in[3], (const float*)d_in[7], (const float*)d_in[11]};
    const float* gg[3] = {(const float*)d_in[4], (const float*)d_in[8], (const float*)d_in[12]};
    const float* be[3] = {(const float*)d_in[5], (const float*)d_in[9], (const float*)d_in[13]};
    const float* Wc1 = (const float*)d_in[14];
    const float* bc1 = (const float*)d_in[15];
    const float* Wc2 = (const float*)d_in[16];
    const float* bc2 = (const float*)d_in[17];
    float* out = (float*)d_out;

    const size_t SZ_XT = (size_t)TOT * CH * 4;               // 32 MiB each
    char* ws = (char*)d_ws;
    float* xtA  = (float*)(ws);
    float* xtB  = (float*)(ws + SZ_XT);
    int*   idxB = (int*)  (ws + 2 * SZ_XT);                  // 320 KiB
    float* psum = (float*)(ws + 2 * SZ_XT + 0x50000);        // 256 KiB
    float* psq  = psum + 128 * CH;                           // 256 KiB
    float* mv   = psq  + 128 * CH;                           // 4 KiB

    transpose_kernel<<<dim3(NPTS / 32, CH / 32, NB), 256, 0, stream>>>(x, xtA);
    knn_kernel<<<dim3(NB * 64), 256, 0, stream>>>(pos, idxB);

    float* cur = xtA;
    float* nxt = xtB;
    for (int blk = 0; blk < 3; ++blk) {
        mr_gemm_mfma<<<dim3(CH / 128, TOT / 128), 256, 0, stream>>>(cur, idxB, W[blk], bb[blk], nxt);
        stats1_kernel<<<dim3(TOT / 128), 256, 0, stream>>>(nxt, psum, psq);
        stats2_kernel<<<dim3(2), 256, 0, stream>>>(psum, psq, mv);
        bnorm_relu_kernel<<<dim3((size_t)TOT * CH / 256), 256, 0, stream>>>(nxt, mv, gg[blk], be[blk]);
        float* t = cur; cur = nxt; nxt = t;
    }
    float* h = nxt;   // after 3 swaps: cur = xtB, nxt = xtA (free)
    gemm_tn<true><<<dim3(256 / 128, TOT / 128), 256, 0, stream>>>(cur, Wc1, bc1, h,
                                                                  TOT, 256, CH);
    head2_kernel<<<dim3(TOT / 4), 256, 0, stream>>>(h, Wc2, bc2, out);
}

// Round 18
// 501.579 us; speedup vs baseline: 4.7329x; 1.4482x over previous
//
#include <hip/hip_runtime.h>

#define NPTS 4096
#define NB   4
#define CH   512
#define TOT  (NB * NPTS)   // 16384
#define KNN  5

typedef _Float16 half8_t __attribute__((ext_vector_type(8)));
typedef float    f32x4   __attribute__((ext_vector_type(4)));

// ---------------- transpose: x [B,C,N] -> xt16 [B*N, C] (f16) ----------------
__global__ __launch_bounds__(256) void transpose_kernel(const float* __restrict__ x,
                                                        _Float16* __restrict__ xt) {
    __shared__ float tile[32][33];
    int b  = blockIdx.z;
    int n0 = blockIdx.x * 32, c0 = blockIdx.y * 32;
    int tx = threadIdx.x & 31, ty = threadIdx.x >> 5;
    const float* xp = x + ((size_t)b * CH + c0) * NPTS + n0;
#pragma unroll
    for (int i = 0; i < 32; i += 8)
        tile[ty + i][tx] = xp[(size_t)(ty + i) * NPTS + tx];   // tile[chan][n]
    __syncthreads();
    int t2 = threadIdx.x & 15, rr = threadIdx.x >> 4;          // 16 col-pairs x 16 rows
#pragma unroll
    for (int i = 0; i < 32; i += 16) {
        int nn = rr + i;
        union { unsigned u; _Float16 h[2]; } o;
        o.h[0] = (_Float16)tile[2 * t2][nn];
        o.h[1] = (_Float16)tile[2 * t2 + 1][nn];
        *(unsigned*)(xt + ((size_t)b * NPTS + n0 + nn) * CH + c0 + 2 * t2) = o.u;
    }
}

// ---------------- KNN: FROZEN (r14/r16 bit-exact) ----------------
__global__ __launch_bounds__(256) void knn_kernel(const float* __restrict__ pos,
                                                  int* __restrict__ idxOut) {
#pragma clang fp contract(off)
    __shared__ float cx[NPTS];
    __shared__ float cy[NPTS];
    __shared__ float d2s[NPTS];
    __shared__ float cd[4][64][KNN];
    __shared__ int   ci[4][64][KNN];
    const int b  = blockIdx.x >> 6;
    const int q0 = (blockIdx.x & 63) << 6;
    const int wv = threadIdx.x >> 6;
    const int ln = threadIdx.x & 63;
    const int n  = q0 + ln;
    const float2* P = (const float2*)(pos + (size_t)b * NPTS * 2);
    for (int m = threadIdx.x; m < NPTS; m += 256) {
        float2 c = P[m];
        cx[m] = c.x; cy[m] = c.y;
        float xx = c.x * c.x;
        float yy = c.y * c.y;
        d2s[m] = xx + yy;
    }
    __syncthreads();
    const float xq = cx[n], yq = cy[n], d2q = d2s[n];
    float bd0 = 3.4e38f, bd1 = 3.4e38f, bd2 = 3.4e38f, bd3 = 3.4e38f, bd4 = 3.4e38f;
    int   bi0 = 0, bi1 = 0, bi2 = 0, bi3 = 0, bi4 = 0;
    const int m0 = wv << 10, m1 = m0 + 1024;
    for (int m = m0; m < m1; m += 4) {
        float dist[4];
#pragma unroll
        for (int u = 0; u < 4; ++u) {
            float px  = xq * cx[m + u];
            float dot = __builtin_fmaf(yq, cy[m + u], px);
            float s   = d2q + d2s[m + u];
            float t2  = 2.0f * dot;
            dist[u] = s - t2;
        }
        float mn = fminf(fminf(dist[0], dist[1]), fminf(dist[2], dist[3]));
        if (mn < bd4) {
#pragma unroll
            for (int u = 0; u < 4; ++u) {
                float d = dist[u];
                if (d < bd4) {
                    bd4 = d; bi4 = m + u;
                    if (bd4 < bd3) { float t = bd3; bd3 = bd4; bd4 = t; int v = bi3; bi3 = bi4; bi4 = v; }
                    if (bd3 < bd2) { float t = bd2; bd2 = bd3; bd3 = t; int v = bi2; bi2 = bi3; bi3 = v; }
                    if (bd2 < bd1) { float t = bd1; bd1 = bd2; bd2 = t; int v = bi1; bi1 = bi2; bi2 = v; }
                    if (bd1 < bd0) { float t = bd0; bd0 = bd1; bd1 = t; int v = bi0; bi0 = bi1; bi1 = v; }
                }
            }
        }
    }
    cd[wv][ln][0] = bd0; cd[wv][ln][1] = bd1; cd[wv][ln][2] = bd2; cd[wv][ln][3] = bd3; cd[wv][ln][4] = bd4;
    ci[wv][ln][0] = bi0; ci[wv][ln][1] = bi1; ci[wv][ln][2] = bi2; ci[wv][ln][3] = bi3; ci[wv][ln][4] = bi4;
    __syncthreads();
    if (wv == 0) {
        float md0 = 3.4e38f, md1 = 3.4e38f, md2 = 3.4e38f, md3 = 3.4e38f, md4 = 3.4e38f;
        int   mi0 = 0, mi1 = 0, mi2 = 0, mi3 = 0, mi4 = 0;
#pragma unroll
        for (int w = 0; w < 4; ++w) {
#pragma unroll
            for (int j = 0; j < KNN; ++j) {
                float d = cd[w][ln][j];
                int  id = ci[w][ln][j];
                if (d < md4) {
                    md4 = d; mi4 = id;
                    if (md4 < md3) { float t = md3; md3 = md4; md4 = t; int v = mi3; mi3 = mi4; mi4 = v; }
                    if (md3 < md2) { float t = md2; md2 = md3; md3 = t; int v = mi2; mi2 = mi3; mi3 = v; }
                    if (md2 < md1) { float t = md1; md1 = md2; md2 = t; int v = mi1; mi1 = mi2; mi2 = v; }
                    if (md1 < md0) { float t = md0; md0 = md1; md1 = t; int v = mi0; mi0 = mi1; mi1 = v; }
                }
            }
        }
        int* op = idxOut + ((size_t)b * NPTS + n) * KNN;
        op[0] = mi0; op[1] = mi1; op[2] = mi2; op[3] = mi3; op[4] = mi4;
    }
}

// ---------------- f32 -> f16 convert (weights, once) ----------------
__global__ __launch_bounds__(256) void convert_kernel(const float* __restrict__ in,
                                                      _Float16* __restrict__ out, int n4) {
    int i = blockIdx.x * 256 + threadIdx.x;
    if (i < n4) {
        float4 v = ((const float4*)in)[i];
        union { unsigned long long u; _Float16 h[4]; } o;
        o.h[0] = (_Float16)v.x; o.h[1] = (_Float16)v.y;
        o.h[2] = (_Float16)v.z; o.h[3] = (_Float16)v.w;
        *(unsigned long long*)(out + (size_t)i * 4) = o.u;
    }
}

// ---------------- feat build: xt16 -> feat16 [TOT, 2CH] interleaved ----------------
__global__ __launch_bounds__(256) void feat_kernel(const _Float16* __restrict__ xt,
                                                   const int* __restrict__ idx,
                                                   _Float16* __restrict__ feat) {
    const int p    = blockIdx.x;
    const int base = p & ~(NPTS - 1);
    const int* ip  = idx + (size_t)p * KNN;
    const _Float16* xr = xt + (size_t)p * CH;
    const _Float16* g0 = xt + (size_t)(base + ip[0]) * CH;
    const _Float16* g1 = xt + (size_t)(base + ip[1]) * CH;
    const _Float16* g2 = xt + (size_t)(base + ip[2]) * CH;
    const _Float16* g3 = xt + (size_t)(base + ip[3]) * CH;
    const _Float16* g4 = xt + (size_t)(base + ip[4]) * CH;
    const int c = threadIdx.x * 2;
    union { unsigned u; _Float16 h[2]; } ux, u0, u1, u2, u3, u4;
    ux.u = *(const unsigned*)(xr + c);
    u0.u = *(const unsigned*)(g0 + c);
    u1.u = *(const unsigned*)(g1 + c);
    u2.u = *(const unsigned*)(g2 + c);
    u3.u = *(const unsigned*)(g3 + c);
    u4.u = *(const unsigned*)(g4 + c);
    union { uint2 v; _Float16 h[4]; } o;
#pragma unroll
    for (int j = 0; j < 2; ++j) {
        float xv = (float)ux.h[j];
        float mr = fmaxf(fmaxf(fmaxf((float)u0.h[j], (float)u1.h[j]),
                               fmaxf((float)u2.h[j], (float)u3.h[j])), (float)u4.h[j]) - xv;
        o.h[2 * j]     = ux.h[j];
        o.h[2 * j + 1] = (_Float16)mr;
    }
    *(uint2*)(feat + (size_t)p * 2 * CH + 2 * c) = o.v;
}

// ---------------- f16 MFMA GEMM: C[M,N] = A[M,K] @ B[N,K]^T + bias ----------------
// 128x128 tile, BK=64, 4 waves (2x2), 16x16x32 MFMA, optional relu / fused BN stats.
template <bool RELU, bool STATS>
__global__ __launch_bounds__(256) void gemm_f16(const _Float16* __restrict__ A,
                                                const _Float16* __restrict__ B,
                                                const float* __restrict__ bias,
                                                float* __restrict__ C,
                                                int N, int K,
                                                float* __restrict__ psum,
                                                float* __restrict__ psq) {
    __shared__ _Float16 As[128][72];
    __shared__ _Float16 Bs[128][72];
    const int tid = threadIdx.x;
    const int bm = blockIdx.y * 128;
    const int bn = blockIdx.x * 128;
    const int r  = tid >> 1;
    const int hf = tid & 1;                    // 32-half chunk within BK=64
    const _Float16* Ap = A + (size_t)(bm + r) * K + hf * 32;
    const _Float16* Bp = B + (size_t)(bn + r) * K + hf * 32;
    const int wv = tid >> 6, ln = tid & 63;
    const int wm = (wv >> 1) * 64, wn = (wv & 1) * 64;
    const int lq = ln >> 4, lc = ln & 15;
    f32x4 zero = {0.0f, 0.0f, 0.0f, 0.0f};
    f32x4 acc[4][4];
#pragma unroll
    for (int i = 0; i < 4; ++i)
#pragma unroll
        for (int j = 0; j < 4; ++j) acc[i][j] = zero;

    for (int k0 = 0; k0 < K; k0 += 64) {
        float4 av[2], bv[2];
        av[0] = ((const float4*)(Ap + k0))[0];
        av[1] = ((const float4*)(Ap + k0))[1];
        av[0] = av[0]; // keep order
        float4 av2 = ((const float4*)(Ap + k0))[2];
        float4 av3 = ((const float4*)(Ap + k0))[3];
        bv[0] = ((const float4*)(Bp + k0))[0];
        bv[1] = ((const float4*)(Bp + k0))[1];
        float4 bv2 = ((const float4*)(Bp + k0))[2];
        float4 bv3 = ((const float4*)(Bp + k0))[3];
        __syncthreads();
        ((float4*)&As[r][hf * 32])[0] = av[0];
        ((float4*)&As[r][hf * 32])[1] = av[1];
        ((float4*)&As[r][hf * 32])[2] = av2;
        ((float4*)&As[r][hf * 32])[3] = av3;
        ((float4*)&Bs[r][hf * 32])[0] = bv[0];
        ((float4*)&Bs[r][hf * 32])[1] = bv[1];
        ((float4*)&Bs[r][hf * 32])[2] = bv2;
        ((float4*)&Bs[r][hf * 32])[3] = bv3;
        __syncthreads();
#pragma unroll
        for (int kc = 0; kc < 2; ++kc) {
            half8_t af[4], bf[4];
#pragma unroll
            for (int mt = 0; mt < 4; ++mt)
                af[mt] = *(const half8_t*)&As[wm + mt * 16 + lc][kc * 32 + lq * 8];
#pragma unroll
            for (int nt = 0; nt < 4; ++nt)
                bf[nt] = *(const half8_t*)&Bs[wn + nt * 16 + lc][kc * 32 + lq * 8];
#pragma unroll
            for (int mt = 0; mt < 4; ++mt)
#pragma unroll
                for (int nt = 0; nt < 4; ++nt)
                    acc[mt][nt] = __builtin_amdgcn_mfma_f32_16x16x32_f16(af[mt], bf[nt],
                                                                         acc[mt][nt], 0, 0, 0);
        }
    }
    // epilogue: C/D layout col=lane&15, row=quad*4+reg
#pragma unroll
    for (int nt = 0; nt < 4; ++nt) {
        const int col = bn + wn + nt * 16 + lc;
        const float bv = bias[col];
        float s = 0.0f, q = 0.0f;
#pragma unroll
        for (int mt = 0; mt < 4; ++mt) {
#pragma unroll
            for (int v = 0; v < 4; ++v) {
                const int row = bm + wm + mt * 16 + lq * 4 + v;
                float val = acc[mt][nt][v] + bv;
                if (RELU) val = fmaxf(val, 0.0f);
                C[(size_t)row * N + col] = val;
                if (STATS) { s += val; q += val * val; }
            }
        }
        if (STATS) {
            s += __shfl_xor(s, 16); s += __shfl_xor(s, 32);
            q += __shfl_xor(q, 16); q += __shfl_xor(q, 32);
            if (lq == 0) {
                atomicAdd(&psum[col], s);
                atomicAdd(&psq[col], q);
            }
        }
    }
}

// ---------------- BN finalize ----------------
__global__ __launch_bounds__(256) void stats2_kernel(const float* __restrict__ psum,
                                                     const float* __restrict__ psq,
                                                     float* __restrict__ mv) {
    int c = blockIdx.x * 256 + threadIdx.x;
    float mean = psum[c] * (1.0f / 16384.0f);
    float var  = psq[c] * (1.0f / 16384.0f) - mean * mean;
    mv[c]      = mean;
    mv[CH + c] = 1.0f / sqrtf(var + 1e-5f);
}

// ---------------- y(f32) -> relu(bnorm) -> xt16 (f16) ----------------
__global__ __launch_bounds__(256) void bnorm_relu_f16(const float4* __restrict__ y,
                                                      const float* __restrict__ mv,
                                                      const float* __restrict__ g,
                                                      const float* __restrict__ be,
                                                      _Float16* __restrict__ xt) {
    size_t i = (size_t)blockIdx.x * 256 + threadIdx.x;   // over TOT*CH/4
    int c0 = (int)((i * 4) & (CH - 1));
    float4 v = y[i];
    union { uint2 w; _Float16 h[4]; } o;
    float vv[4] = {v.x, v.y, v.z, v.w};
#pragma unroll
    for (int k = 0; k < 4; ++k) {
        int c = c0 + k;
        float t = ((vv[k] - mv[c]) * mv[CH + c]) * g[c] + be[c];
        o.h[k] = (_Float16)fmaxf(t, 0.0f);
    }
    *(uint2*)((_Float16*)xt + i * 4) = o.w;
}

// ---------------- head stage 2 (shuffle) ----------------
__global__ __launch_bounds__(256) void head2_kernel(const float* __restrict__ h,
                                                    const float* __restrict__ Wc2,
                                                    const float* __restrict__ bc2,
                                                    float* __restrict__ out) {
    const int wave = threadIdx.x >> 6, lane = threadIdx.x & 63;
    const int p = blockIdx.x * 4 + wave;
    const float* hp = h + (size_t)p * 256;
    float acc[5] = {0.f, 0.f, 0.f, 0.f, 0.f};
#pragma unroll
    for (int fo = 0; fo < 4; ++fo) {
        int f = lane + fo * 64;
        float hv = hp[f];
#pragma unroll
        for (int j = 0; j < 5; ++j) acc[j] += hv * Wc2[j * 256 + f];
    }
#pragma unroll
    for (int j = 0; j < 5; ++j)
#pragma unroll
        for (int off = 32; off; off >>= 1) acc[j] += __shfl_down(acc[j], off);
    if (lane == 0) {
#pragma unroll
        for (int j = 0; j < 5; ++j) out[(size_t)p * 5 + j] = acc[j] + bc2[j];
    }
}

extern "C" void kernel_launch(void* const* d_in, const int* in_sizes, int n_in,
                              void* d_out, int out_size, void* d_ws, size_t ws_size,
                              hipStream_t stream) {
    const float* x   = (const float*)d_in[0];
    const float* pos = (const float*)d_in[1];
    const float* W[3]  = {(const float*)d_in[2], (const float*)d_in[6], (const float*)d_in[10]};
    const float* bb[3] = {(const float*)d_in[3], (const float*)d_in[7], (const float*)d_in[11]};
    const float* gg[3] = {(const float*)d_in[4], (const float*)d_in[8], (const float*)d_in[12]};
    const float* be[3] = {(const float*)d_in[5], (const float*)d_in[9], (const float*)d_in[13]};
    const float* Wc1 = (const float*)d_in[14];
    const float* bc1 = (const float*)d_in[15];
    const float* Wc2 = (const float*)d_in[16];
    const float* bc2 = (const float*)d_in[17];
    float* out = (float*)d_out;

    const size_t MB = 1ull << 20;
    char* ws = (char*)d_ws;
    _Float16* xtA16  = (_Float16*)(ws);                  // 16 MB
    _Float16* xtB16  = (_Float16*)(ws + 16 * MB);        // 16 MB
    _Float16* feat16 = (_Float16*)(ws + 32 * MB);        // 32 MB
    float*    y      = (float*)   (ws + 64 * MB);        // 32 MB (reused as h at head)
    _Float16* w16[3] = {(_Float16*)(ws + 96 * MB), (_Float16*)(ws + 97 * MB),
                        (_Float16*)(ws + 98 * MB)};      // 1 MB each
    _Float16* wc116  = (_Float16*)(ws + 99 * MB);        // 256 KB
    int*      idxB   = (int*)     (ws + 100 * MB);       // 320 KB
    float*    psum   = (float*)   (ws + 101 * MB);
    float*    psq    = psum + CH;
    float*    mv     = psq + CH;

    transpose_kernel<<<dim3(NPTS / 32, CH / 32, NB), 256, 0, stream>>>(x, xtA16);
    knn_kernel<<<dim3(NB * 64), 256, 0, stream>>>(pos, idxB);
    for (int i = 0; i < 3; ++i)
        convert_kernel<<<dim3((CH * 2 * CH / 4 + 255) / 256), 256, 0, stream>>>(W[i], w16[i],
                                                                                CH * 2 * CH / 4);
    convert_kernel<<<dim3((256 * CH / 4 + 255) / 256), 256, 0, stream>>>(Wc1, wc116, 256 * CH / 4);

    _Float16* cur = xtA16;
    _Float16* nxt = xtB16;
    for (int blk = 0; blk < 3; ++blk) {
        feat_kernel<<<dim3(TOT), 256, 0, stream>>>(cur, idxB, feat16);
        hipMemsetAsync(psum, 0, 2 * CH * sizeof(float), stream);
        gemm_f16<false, true><<<dim3(CH / 128, TOT / 128), 256, 0, stream>>>(
            feat16, w16[blk], bb[blk], y, CH, 2 * CH, psum, psq);
        stats2_kernel<<<dim3(2), 256, 0, stream>>>(psum, psq, mv);
        bnorm_relu_f16<<<dim3((size_t)TOT * CH / 4 / 256), 256, 0, stream>>>(
            (const float4*)y, mv, gg[blk], be[blk], nxt);
        _Float16* t = cur; cur = nxt; nxt = t;
    }
    float* h = y;   // y free after last bnorm
    gemm_f16<true, false><<<dim3(256 / 128, TOT / 128), 256, 0, stream>>>(
        cur, wc116, bc1, h, 256, CH, nullptr, nullptr);
    head2_kernel<<<dim3(TOT / 4), 256, 0, stream>>>(h, Wc2, bc2, out);
}